// Round 2
// baseline (225.726 us; speedup 1.0000x reference)
//
#include <hip/hip_runtime.h>

#define WIN      2048
#define HOP      512
#define NFRAMES  16384
#define NBINS    1025   // WIN/2 + 1

// ---------------------------------------------------------------------------
// init: synthesis window rs[j] = (hamming/sqrt(4094)) / env, folded with the
// 1/1024 normalization of the half-size complex IFFT.
// ---------------------------------------------------------------------------
__global__ void init_rs_kernel(float* __restrict__ rs) {
    int i = blockIdx.x * blockDim.x + threadIdx.x;
    if (i >= WIN) return;
    const float inv2047 = 1.0f / 2047.0f;
    const float scale   = rsqrtf(4094.0f);       // 1/sqrt(fft_size=(win-1)*2)
    float sw = (0.54f - 0.46f * cospif(2.0f * (float)i * inv2047)) * scale;
    int   m0 = i & 511;
    float env = 0.0f;
    #pragma unroll
    for (int r = 0; r < 4; ++r) {
        int   m = m0 + 512 * r;
        float h = (0.54f - 0.46f * cospif(2.0f * (float)m * inv2047)) * scale;
        env += h * h;
    }
    rs[i] = sw / env * (1.0f / 1024.0f);         // fold half-size IFFT 1/N
}

// padded LDS index: breaks the 16-way conflict of the s=4 stage's writes
__device__ __forceinline__ int pidx(int a) { return a + (a >> 3); }

// ---------------------------------------------------------------------------
// one workgroup (256 threads) per frame:
//  A. stage spectrum X[0..1024] into LDS (imag of DC/Nyquist zeroed)
//  B. pack to Zf[0..1023] for the half-size complex inverse FFT:
//     E  = (X[k] + conj(X[1024-k]))/2
//     O' = -i/2 * e^{+2pi i k/2048} * (conj(X[1024-k]) - X[k]);  Zf = E + O'
//  C. 1024-point unnormalized inverse FFT, 5 fused radix-4 Stockham stages
//  D. unpack x[2n]=Re z[n], x[2n+1]=Im z[n]; fftshift; window; atomic OLA
// ---------------------------------------------------------------------------
__global__ __launch_bounds__(256) void istft_kernel(
        const float* __restrict__ mag, const float* __restrict__ ph,
        const float* __restrict__ rs, float* __restrict__ out, int out_size) {
    __shared__ float2 bufA[1152];   // 1024 + 128 pad
    __shared__ float2 bufB[1152];   // also holds X (raw idx) during phase A/B
    __shared__ float2 tw[256];      // e^{2pi i g/1024}, g in [0,256)

    const int tid   = threadIdx.x;
    const int frame = blockIdx.x;
    const float* magf = mag + (size_t)frame * NBINS;
    const float* phf  = ph  + (size_t)frame * NBINS;

    // twiddle table (one entry per thread)
    {
        float s, c;
        sincospif((float)tid * (1.0f / 512.0f), &s, &c);
        tw[tid] = make_float2(c, s);
    }

    // A: spectrum into bufB (raw indexing, 1025 entries)
    for (int k = tid; k < NBINS; k += 256) {
        float m = magf[k], p = phf[k];
        float s, c;
        sincosf(p, &s, &c);
        float re = m * c, im = m * s;
        if (k == 0 || k == 1024) im = 0.0f;
        bufB[k] = make_float2(re, im);
    }
    __syncthreads();

    // B: pack Zf into bufA (padded indexing)
    #pragma unroll
    for (int j = 0; j < 4; ++j) {
        int k = tid + j * 256;                   // 0..1023
        float2 Xk = bufB[k];
        float2 Xm = bufB[1024 - k];
        float s, c;
        sincospif((float)k * (1.0f / 1024.0f), &s, &c);   // e^{2pi i k/2048}
        float Er = 0.5f * (Xk.x + Xm.x), Ei = 0.5f * (Xk.y - Xm.y);
        float Tr = Xm.x - Xk.x,          Ti = -Xm.y - Xk.y;
        float Or = 0.5f * (c * Ti + s * Tr);
        float Oi = 0.5f * (s * Ti - c * Tr);
        bufA[pidx(k)] = make_float2(Er + Or, Ei + Oi);
    }
    __syncthreads();

    // C: 5 fused radix-4 stages (s = 1,4,16,64,256), ping-pong A<->B
    float2* src = bufA;
    float2* dst = bufB;
    #pragma unroll
    for (int t = 0; t < 5; ++t) {
        const int s4 = 1 << (2 * t);
        const int c  = tid;
        const int G  = c & ~(s4 - 1);            // floor(c/s)*s
        float2 x0 = src[pidx(c)];
        float2 x1 = src[pidx(c + 256)];
        float2 x2 = src[pidx(c + 512)];
        float2 x3 = src[pidx(c + 768)];
        float2 w  = tw[G];
        // u0=x0+x2; u1=(x0-x2)w; u2=x1+x3; u3=(x1-x3)*(i w)
        float2 u0 = make_float2(x0.x + x2.x, x0.y + x2.y);
        float  ar = x0.x - x2.x, ai = x0.y - x2.y;
        float2 u1 = make_float2(ar * w.x - ai * w.y, ar * w.y + ai * w.x);
        float2 u2 = make_float2(x1.x + x3.x, x1.y + x3.y);
        float  br = x1.x - x3.x, bi = x1.y - x3.y;
        float2 u3 = make_float2(-br * w.y - bi * w.x, br * w.x - bi * w.y);
        float2 w2 = make_float2(w.x * w.x - w.y * w.y, 2.0f * w.x * w.y);
        const int base = c + 3 * G;
        dst[pidx(base)]          = make_float2(u0.x + u2.x, u0.y + u2.y);
        dst[pidx(base + s4)]     = make_float2(u1.x + u3.x, u1.y + u3.y);
        float dr = u0.x - u2.x, di = u0.y - u2.y;
        dst[pidx(base + 2 * s4)] = make_float2(dr * w2.x - di * w2.y,
                                               dr * w2.y + di * w2.x);
        float er = u1.x - u3.x, ei = u1.y - u3.y;
        dst[pidx(base + 3 * s4)] = make_float2(er * w2.x - ei * w2.y,
                                               er * w2.y + ei * w2.x);
        __syncthreads();
        float2* tmp = src; src = dst; dst = tmp;
    }
    // z[n] now in src (= bufB), padded indexing

    // D: unpack + fftshift + window + overlap-add
    const float2* rs2   = (const float2*)rs;
    const long    base0 = (long)frame * HOP - 1536;   // 3*hop trim
    #pragma unroll
    for (int q = 0; q < 4; ++q) {
        int   t2 = tid + q * 256;                // output pair j = 2*t2
        int   n  = (t2 + 512) & 1023;            // fftshift: m=(j+1024)&2047, n=m/2
        float2 z = src[pidx(n)];
        float2 r = rs2[t2];
        long p0 = base0 + 2 * t2;
        float v0 = z.x * r.x;
        float v1 = z.y * r.y;
        if (p0 >= 0 && p0 < out_size)     atomicAdd(out + p0,     v0);
        if (p0 + 1 >= 0 && p0 + 1 < out_size) atomicAdd(out + p0 + 1, v1);
    }
}

extern "C" void kernel_launch(void* const* d_in, const int* in_sizes, int n_in,
                              void* d_out, int out_size, void* d_ws, size_t ws_size,
                              hipStream_t stream) {
    const float* mag = (const float*)d_in[0];
    const float* ph  = (const float*)d_in[1];
    float* out = (float*)d_out;
    float* rs  = (float*)d_ws;                   // 2048 floats = 8 KB scratch

    hipMemsetAsync(d_out, 0, (size_t)out_size * sizeof(float), stream);
    init_rs_kernel<<<(WIN + 255) / 256, 256, 0, stream>>>(rs);
    istft_kernel<<<NFRAMES, 256, 0, stream>>>(mag, ph, rs, out, out_size);
}

// Round 3
// 116.904 us; speedup vs baseline: 1.9309x; 1.9309x over previous
//
#include <hip/hip_runtime.h>

#define WIN      2048
#define HOP      512
#define NFRAMES  16384
#define NBINS    1025      // WIN/2 + 1
#define FPB      8         // frames per block
#define ACCN     (FPB * HOP + (WIN - HOP))   // 5632 LDS accumulator floats

// ---------------------------------------------------------------------------
// init: synthesis window rs[j] = (hamming/sqrt(4094)) / env, folded with the
// 1/1024 normalization of the half-size complex IFFT.
// ---------------------------------------------------------------------------
__global__ void init_rs_kernel(float* __restrict__ rs) {
    int i = blockIdx.x * blockDim.x + threadIdx.x;
    if (i >= WIN) return;
    const float inv2047 = 1.0f / 2047.0f;
    const float scale   = rsqrtf(4094.0f);       // 1/sqrt(fft_size=(win-1)*2)
    float sw = (0.54f - 0.46f * cospif(2.0f * (float)i * inv2047)) * scale;
    int   m0 = i & 511;
    float env = 0.0f;
    #pragma unroll
    for (int r = 0; r < 4; ++r) {
        int   m = m0 + 512 * r;
        float h = (0.54f - 0.46f * cospif(2.0f * (float)m * inv2047)) * scale;
        env += h * h;
    }
    rs[i] = sw / env * (1.0f / 1024.0f);         // fold half-size IFFT 1/N
}

// padded LDS index: breaks strided-stage bank conflicts
__device__ __forceinline__ int pidx(int a) { return a + (a >> 3); }

// ---------------------------------------------------------------------------
// one workgroup (256 threads) per 8 consecutive frames:
//  per frame: A. spectrum into LDS  B. pack to half-size Zf
//             C. 1024-pt inverse FFT (5 radix-4 Stockham stages)
//             D. unpack/fftshift/window -> accumulate into LDS OLA buffer
//  E. single writeback: interior plain stores, seams atomicAdd
// ---------------------------------------------------------------------------
__global__ __launch_bounds__(256) void istft_kernel(
        const float* __restrict__ mag, const float* __restrict__ ph,
        const float* __restrict__ rs, float* __restrict__ out, int out_size) {
    __shared__ float2 bufA[1152];        // 1024 + 128 pad
    __shared__ float2 bufB[1152];
    __shared__ float  acc[ACCN];         // block-local overlap-add buffer

    const int tid    = threadIdx.x;
    const int frame0 = blockIdx.x * FPB;

    for (int i = tid; i < ACCN; i += 256) acc[i] = 0.0f;
    const float2* rs2 = (const float2*)rs;

    for (int fi = 0; fi < FPB; ++fi) {
        const float* magf = mag + (size_t)(frame0 + fi) * NBINS;
        const float* phf  = ph  + (size_t)(frame0 + fi) * NBINS;

        // A: spectrum into bufB (raw indexing)
        for (int k = tid; k < NBINS; k += 256) {
            float m = magf[k], p = phf[k];
            float s, c;
            sincosf(p, &s, &c);
            float re = m * c, im = m * s;
            if (k == 0 || k == 1024) im = 0.0f;  // irfft drops DC/Nyquist imag
            bufB[k] = make_float2(re, im);
        }
        __syncthreads();

        // B: pack Zf = E + O' into bufA (padded indexing)
        #pragma unroll
        for (int j = 0; j < 4; ++j) {
            int k = tid + j * 256;               // 0..1023
            float2 Xk = bufB[k];
            float2 Xm = bufB[1024 - k];
            float s, c;
            sincospif((float)k * (1.0f / 1024.0f), &s, &c);  // e^{2pi i k/2048}
            float Er = 0.5f * (Xk.x + Xm.x), Ei = 0.5f * (Xk.y - Xm.y);
            float Tr = Xm.x - Xk.x,          Ti = -Xm.y - Xk.y;
            float Or = 0.5f * (c * Ti + s * Tr);
            float Oi = 0.5f * (s * Ti - c * Tr);
            bufA[pidx(k)] = make_float2(Er + Or, Ei + Oi);
        }
        __syncthreads();

        // C: 5 radix-4 stages (s4 = 1,4,16,64,256), ping-pong A<->B -> ends B
        float2* src = bufA;
        float2* dst = bufB;
        #pragma unroll
        for (int t = 0; t < 5; ++t) {
            const int s4 = 1 << (2 * t);
            const int c  = tid;
            const int G  = c & ~(s4 - 1);
            float2 x0 = src[pidx(c)];
            float2 x1 = src[pidx(c + 256)];
            float2 x2 = src[pidx(c + 512)];
            float2 x3 = src[pidx(c + 768)];
            float sG, cG;
            sincospif((float)G * (1.0f / 512.0f), &sG, &cG);  // e^{2pi i G/1024}
            float2 w = make_float2(cG, sG);
            float2 u0 = make_float2(x0.x + x2.x, x0.y + x2.y);
            float  ar = x0.x - x2.x, ai = x0.y - x2.y;
            float2 u1 = make_float2(ar * w.x - ai * w.y, ar * w.y + ai * w.x);
            float2 u2 = make_float2(x1.x + x3.x, x1.y + x3.y);
            float  br = x1.x - x3.x, bi = x1.y - x3.y;
            float2 u3 = make_float2(-br * w.y - bi * w.x, br * w.x - bi * w.y);
            float2 w2 = make_float2(w.x * w.x - w.y * w.y, 2.0f * w.x * w.y);
            const int base = c + 3 * G;
            dst[pidx(base)]          = make_float2(u0.x + u2.x, u0.y + u2.y);
            dst[pidx(base + s4)]     = make_float2(u1.x + u3.x, u1.y + u3.y);
            float dr = u0.x - u2.x, di = u0.y - u2.y;
            dst[pidx(base + 2 * s4)] = make_float2(dr * w2.x - di * w2.y,
                                                   dr * w2.y + di * w2.x);
            float er = u1.x - u3.x, ei = u1.y - u3.y;
            dst[pidx(base + 3 * s4)] = make_float2(er * w2.x - ei * w2.y,
                                                   er * w2.y + ei * w2.x);
            __syncthreads();
            float2* tmp = src; src = dst; dst = tmp;
        }
        // z[n] in bufB (padded indexing)

        // D: unpack + fftshift + window -> LDS accumulate (race-free: each
        // thread owns indices 2*t2, 2*t2+1)
        #pragma unroll
        for (int q = 0; q < 4; ++q) {
            int   t2 = tid + q * 256;            // output pair j = 2*t2
            int   n  = (t2 + 512) & 1023;        // fftshift
            float2 z = bufB[pidx(n)];
            float2 r = rs2[t2];
            int a = fi * HOP + 2 * t2;
            acc[a]     += z.x * r.x;
            acc[a + 1] += z.y * r.y;
        }
        __syncthreads();                         // before next frame reuses bufs
    }

    // E: writeback. Global position p = frame0*HOP + a - 1536 (3*hop trim).
    // Interior a in [1536, FPB*HOP): all 4 contributors local -> plain store.
    const int base = frame0 * HOP - 1536;
    for (int a = tid; a < ACCN; a += 256) {
        int p = base + a;
        if (p < 0 || p >= out_size) continue;
        float v = acc[a];
        if (a >= (WIN - HOP) && a < FPB * HOP) out[p] = v;
        else                                   atomicAdd(out + p, v);
    }
}

extern "C" void kernel_launch(void* const* d_in, const int* in_sizes, int n_in,
                              void* d_out, int out_size, void* d_ws, size_t ws_size,
                              hipStream_t stream) {
    const float* mag = (const float*)d_in[0];
    const float* ph  = (const float*)d_in[1];
    float* out = (float*)d_out;
    float* rs  = (float*)d_ws;                   // 2048 floats = 8 KB scratch

    hipMemsetAsync(d_out, 0, (size_t)out_size * sizeof(float), stream);
    init_rs_kernel<<<(WIN + 255) / 256, 256, 0, stream>>>(rs);
    istft_kernel<<<NFRAMES / FPB, 256, 0, stream>>>(mag, ph, rs, out, out_size);
}

// Round 4
// 80.981 us; speedup vs baseline: 2.7874x; 1.4436x over previous
//
#include <hip/hip_runtime.h>

#define WIN      2048
#define HOP      512
#define NFRAMES  16384
#define NBINS    1025      // WIN/2 + 1
#define FPB      8         // frames per block
#define ACCN     (FPB * HOP + (WIN - HOP))   // 5632 floats

// ---------------------------------------------------------------------------
// init: synthesis window rs[j] = (hamming/sqrt(4094)) / env, folded with the
// 1/1024 normalization of the half-size complex IFFT.
// ---------------------------------------------------------------------------
__global__ void init_rs_kernel(float* __restrict__ rs) {
    int i = blockIdx.x * blockDim.x + threadIdx.x;
    if (i >= WIN) return;
    const float inv2047 = 1.0f / 2047.0f;
    const float scale   = rsqrtf(4094.0f);
    float sw = (0.54f - 0.46f * cospif(2.0f * (float)i * inv2047)) * scale;
    int   m0 = i & 511;
    float env = 0.0f;
    #pragma unroll
    for (int r = 0; r < 4; ++r) {
        int   m = m0 + 512 * r;
        float h = (0.54f - 0.46f * cospif(2.0f * (float)m * inv2047)) * scale;
        env += h * h;
    }
    rs[i] = sw / env * (1.0f / 1024.0f);
}

__device__ __forceinline__ int pidx(int a) { return a + (a >> 3); }
__device__ __forceinline__ float2 cmul(float2 a, float2 b) {
    return make_float2(a.x * b.x - a.y * b.y, a.x * b.y + a.y * b.x);
}

// ---------------------------------------------------------------------------
// one workgroup (256 threads) per 8 frames. Per frame:
//  A: spectrum X[0..1024] -> LDS (hw sincos)       [1 barrier]
//  B+s0: half-size pack fused with radix-4 stage0  [1 barrier]
//  s1..s3: radix-4 Stockham, reg-hoisted twiddles  [3 barriers]
//  s4+D: twiddle-free last stage fused with fftshift/window/LDS-OLA [1 barrier]
// then one writeback: interior plain stores, seams atomicAdd.
// ---------------------------------------------------------------------------
__global__ __launch_bounds__(256, 4) void istft_kernel(
        const float* __restrict__ mag, const float* __restrict__ ph,
        const float* __restrict__ rs, float* __restrict__ out, int out_size) {
    __shared__ float2 bufA[1152];        // 1024 + pad
    __shared__ float2 bufB[1152];
    __shared__ float2 acc2[ACCN / 2];    // block-local OLA (as float2)
    float* acc = (float*)acc2;

    const int tid    = threadIdx.x;
    const int frame0 = blockIdx.x * FPB;

    // ---- frame-invariant per-thread constants ----
    float2 wpk;                                    // e^{2pi i tid/2048}
    sincospif((float)tid * (1.0f / 1024.0f), &wpk.y, &wpk.x);
    float2 wst[4], w2st[4];
    wst[0] = cmul(wpk, wpk);                       // e^{2pi i tid/1024}
    sincospif((float)(tid & ~3)  * (1.0f / 512.0f), &wst[1].y, &wst[1].x);
    sincospif((float)(tid & ~15) * (1.0f / 512.0f), &wst[2].y, &wst[2].x);
    sincospif((float)(tid & ~63) * (1.0f / 512.0f), &wst[3].y, &wst[3].x);
    #pragma unroll
    for (int t = 0; t < 4; ++t) w2st[t] = cmul(wst[t], wst[t]);

    const float2* rs2 = (const float2*)rs;
    const float2 r0 = rs2[tid], r1 = rs2[tid + 256],
                 r2 = rs2[tid + 512], r3 = rs2[tid + 768];
    const float RT = 0.70710678118654752f;         // sqrt(2)/2

    for (int i = tid; i < ACCN; i += 256) acc[i] = 0.0f;
    // (first-frame barriers below order acc-zero before first OLA RMW)

    for (int fi = 0; fi < FPB; ++fi) {
        const float* magf = mag + (size_t)(frame0 + fi) * NBINS;
        const float* phf  = ph  + (size_t)(frame0 + fi) * NBINS;

        // A: spectrum into bufB (raw indexing)
        for (int k = tid; k < NBINS; k += 256) {
            float s, c;
            __sincosf(phf[k], &s, &c);
            float m = magf[k];
            float re = m * c, im = m * s;
            if (k == 0 || k == 1024) im = 0.0f;
            bufB[k] = make_float2(re, im);
        }
        __syncthreads();

        // B + stage0 (fused in registers) -> bufA
        {
            float2 z[4];
            #pragma unroll
            for (int j = 0; j < 4; ++j) {
                int k = tid + j * 256;
                float2 Xk = bufB[k];
                float2 Xm = bufB[1024 - k];
                float2 wj;                         // wpk * e^{i pi j/4}
                if      (j == 0) wj = wpk;
                else if (j == 1) wj = make_float2(RT * (wpk.x - wpk.y), RT * (wpk.x + wpk.y));
                else if (j == 2) wj = make_float2(-wpk.y, wpk.x);
                else             wj = make_float2(-RT * (wpk.x + wpk.y), RT * (wpk.x - wpk.y));
                float Er = 0.5f * (Xk.x + Xm.x), Ei = 0.5f * (Xk.y - Xm.y);
                float Tr = Xm.x - Xk.x,          Ti = -Xm.y - Xk.y;
                float Or = 0.5f * (wj.x * Ti + wj.y * Tr);
                float Oi = 0.5f * (wj.y * Ti - wj.x * Tr);
                z[j] = make_float2(Er + Or, Ei + Oi);
            }
            float2 w = wst[0], w2 = w2st[0];
            float2 u0 = make_float2(z[0].x + z[2].x, z[0].y + z[2].y);
            float  ar = z[0].x - z[2].x, ai = z[0].y - z[2].y;
            float2 u1 = make_float2(ar * w.x - ai * w.y, ar * w.y + ai * w.x);
            float2 u2 = make_float2(z[1].x + z[3].x, z[1].y + z[3].y);
            float  br = z[1].x - z[3].x, bi = z[1].y - z[3].y;
            float2 u3 = make_float2(-br * w.y - bi * w.x, br * w.x - bi * w.y);
            const int base = 4 * tid;              // tid + 3*G, G=tid, s4=1
            bufA[pidx(base)]     = make_float2(u0.x + u2.x, u0.y + u2.y);
            bufA[pidx(base + 1)] = make_float2(u1.x + u3.x, u1.y + u3.y);
            float dr = u0.x - u2.x, di = u0.y - u2.y;
            bufA[pidx(base + 2)] = make_float2(dr * w2.x - di * w2.y, dr * w2.y + di * w2.x);
            float er = u1.x - u3.x, ei = u1.y - u3.y;
            bufA[pidx(base + 3)] = make_float2(er * w2.x - ei * w2.y, er * w2.y + ei * w2.x);
        }
        __syncthreads();

        // stages 1..3 (A->B->A->B)
        {
            float2* src = bufA;
            float2* dst = bufB;
            #pragma unroll
            for (int t = 1; t < 4; ++t) {
                const int s4 = 1 << (2 * t);
                const int G  = tid & ~(s4 - 1);
                float2 x0 = src[pidx(tid)];
                float2 x1 = src[pidx(tid + 256)];
                float2 x2 = src[pidx(tid + 512)];
                float2 x3 = src[pidx(tid + 768)];
                float2 w = wst[t], w2 = w2st[t];
                float2 u0 = make_float2(x0.x + x2.x, x0.y + x2.y);
                float  ar = x0.x - x2.x, ai = x0.y - x2.y;
                float2 u1 = make_float2(ar * w.x - ai * w.y, ar * w.y + ai * w.x);
                float2 u2 = make_float2(x1.x + x3.x, x1.y + x3.y);
                float  br = x1.x - x3.x, bi = x1.y - x3.y;
                float2 u3 = make_float2(-br * w.y - bi * w.x, br * w.x - bi * w.y);
                const int base = tid + 3 * G;
                dst[pidx(base)]          = make_float2(u0.x + u2.x, u0.y + u2.y);
                dst[pidx(base + s4)]     = make_float2(u1.x + u3.x, u1.y + u3.y);
                float dr = u0.x - u2.x, di = u0.y - u2.y;
                dst[pidx(base + 2 * s4)] = make_float2(dr * w2.x - di * w2.y, dr * w2.y + di * w2.x);
                float er = u1.x - u3.x, ei = u1.y - u3.y;
                dst[pidx(base + 3 * s4)] = make_float2(er * w2.x - ei * w2.y, er * w2.y + ei * w2.x);
                __syncthreads();
                float2* tmp = src; src = dst; dst = tmp;
            }
        }
        // data now in bufB

        // stage4 (w = w2 = 1) fused with fftshift/window/OLA into acc
        {
            float2 x0 = bufB[pidx(tid)];
            float2 x1 = bufB[pidx(tid + 256)];
            float2 x2 = bufB[pidx(tid + 512)];
            float2 x3 = bufB[pidx(tid + 768)];
            float2 u0 = make_float2(x0.x + x2.x, x0.y + x2.y);
            float2 u1 = make_float2(x0.x - x2.x, x0.y - x2.y);
            float2 u2 = make_float2(x1.x + x3.x, x1.y + x3.y);
            float2 u3 = make_float2(-(x1.y - x3.y), x1.x - x3.x);   // i*(x1-x3)
            const int A0 = fi * 256;
            float2 y, a;
            // n=tid       -> t2=tid+512 (fftshift), window r2
            y = make_float2(u0.x + u2.x, u0.y + u2.y);
            a = acc2[A0 + tid + 512];
            acc2[A0 + tid + 512] = make_float2(a.x + y.x * r2.x, a.y + y.y * r2.y);
            // n=tid+256   -> t2=tid+768, window r3
            y = make_float2(u1.x + u3.x, u1.y + u3.y);
            a = acc2[A0 + tid + 768];
            acc2[A0 + tid + 768] = make_float2(a.x + y.x * r3.x, a.y + y.y * r3.y);
            // n=tid+512   -> t2=tid, window r0
            y = make_float2(u0.x - u2.x, u0.y - u2.y);
            a = acc2[A0 + tid];
            acc2[A0 + tid] = make_float2(a.x + y.x * r0.x, a.y + y.y * r0.y);
            // n=tid+768   -> t2=tid+256, window r1
            y = make_float2(u1.x - u3.x, u1.y - u3.y);
            a = acc2[A0 + tid + 256];
            acc2[A0 + tid + 256] = make_float2(a.x + y.x * r1.x, a.y + y.y * r1.y);
        }
        __syncthreads();
    }

    // E: writeback. p = frame0*HOP + a - 1536. Interior: plain store.
    const int base = frame0 * HOP - 1536;
    for (int a = tid; a < ACCN; a += 256) {
        int p = base + a;
        if (p < 0 || p >= out_size) continue;
        float v = acc[a];
        if (a >= (WIN - HOP) && a < FPB * HOP) out[p] = v;
        else                                   atomicAdd(out + p, v);
    }
}

extern "C" void kernel_launch(void* const* d_in, const int* in_sizes, int n_in,
                              void* d_out, int out_size, void* d_ws, size_t ws_size,
                              hipStream_t stream) {
    const float* mag = (const float*)d_in[0];
    const float* ph  = (const float*)d_in[1];
    float* out = (float*)d_out;
    float* rs  = (float*)d_ws;

    hipMemsetAsync(d_out, 0, (size_t)out_size * sizeof(float), stream);
    init_rs_kernel<<<(WIN + 255) / 256, 256, 0, stream>>>(rs);
    istft_kernel<<<NFRAMES / FPB, 256, 0, stream>>>(mag, ph, rs, out, out_size);
}